// Round 1
// baseline (1446.072 us; speedup 1.0000x reference)
//
#include <hip/hip_runtime.h>
#include <hip/hip_bf16.h>
#include <math.h>

#define B_ 2
#define L_ 1024
#define D_ 1024
#define DI_ 2048
#define K_ 4
#define N_ 16
#define R_ 64
#define BL_ (B_ * L_)
#define EPS_ 1e-5f

// ---------------- LayerNorm: one block per row of D=1024 ----------------
__global__ void ln_kernel(const float* __restrict__ x, const float* __restrict__ w,
                          const float* __restrict__ b, float* __restrict__ h) {
    int row = blockIdx.x;              // 0..BL-1
    const float* xr = x + (size_t)row * D_;
    float4 v = ((const float4*)xr)[threadIdx.x];   // 256 threads * 4 = 1024

    __shared__ float red[4];
    // --- mean ---
    float s = v.x + v.y + v.z + v.w;
    for (int off = 1; off < 64; off <<= 1) s += __shfl_xor(s, off, 64);
    if ((threadIdx.x & 63) == 0) red[threadIdx.x >> 6] = s;
    __syncthreads();
    float mu = (red[0] + red[1] + red[2] + red[3]) * (1.0f / D_);
    __syncthreads();
    // --- var ---
    float cx = v.x - mu, cy = v.y - mu, cz = v.z - mu, cw = v.w - mu;
    float sq = cx*cx + cy*cy + cz*cz + cw*cw;
    for (int off = 1; off < 64; off <<= 1) sq += __shfl_xor(sq, off, 64);
    if ((threadIdx.x & 63) == 0) red[threadIdx.x >> 6] = sq;
    __syncthreads();
    float var = (red[0] + red[1] + red[2] + red[3]) * (1.0f / D_);
    float rstd = rsqrtf(var + EPS_);

    float4 wv = ((const float4*)w)[threadIdx.x];
    float4 bv = ((const float4*)b)[threadIdx.x];
    float4 o;
    o.x = cx * rstd * wv.x + bv.x;
    o.y = cy * rstd * wv.y + bv.y;
    o.z = cz * rstd * wv.z + bv.z;
    o.w = cw * rstd * wv.w + bv.w;
    ((float4*)(h + (size_t)row * D_))[threadIdx.x] = o;
}

// ---------------- Generic fp32 tiled GEMM: C = A(MxK) * B(KxN) ----------------
// EPI 0: none; EPI 1: softplus(acc + bias[col]); EPI 2: acc + add[row*ldc+col]
template <int EPI>
__global__ __launch_bounds__(256) void gemm_kernel(
        const float* __restrict__ A, int lda,
        const float* __restrict__ Bm, int ldb,
        float* __restrict__ C, int ldc,
        int M, int Nn, int Kk,
        const float* __restrict__ bias,
        const float* __restrict__ add) {
    const int BM = 64, BN = 64, BK = 16;
    __shared__ float As[BK][BM + 4];
    __shared__ float Bs[BK][BN];

    int tid = threadIdx.x;
    int m0 = blockIdx.y * BM;
    int n0 = blockIdx.x * BN;

    int ar = tid >> 2;           // 0..63 row within A tile
    int ak = (tid & 3) << 2;     // 0,4,8,12 k-offset
    int kb = tid >> 4;           // 0..15 k row of B tile
    int bc = (tid & 15) << 2;    // 0..60 col offset
    int ty = tid >> 4;           // 0..15
    int tx = tid & 15;           // 0..15

    float acc[4][4] = {};

    for (int k0 = 0; k0 < Kk; k0 += BK) {
        // A tile (M,K multiples of 64/16 for all our calls — unguarded)
        const float* Ap = A + (size_t)(m0 + ar) * lda + (k0 + ak);
        float4 av = *(const float4*)Ap;
        As[ak + 0][ar] = av.x;
        As[ak + 1][ar] = av.y;
        As[ak + 2][ar] = av.z;
        As[ak + 3][ar] = av.w;

        // B tile (guard N edge: N=96 case)
        int bcol = n0 + bc;
        const float* Bp = Bm + (size_t)(k0 + kb) * ldb + bcol;
        float4 bv;
        if (bcol + 3 < Nn) {
            bv = *(const float4*)Bp;
        } else {
            bv.x = (bcol + 0 < Nn) ? Bp[0] : 0.f;
            bv.y = (bcol + 1 < Nn) ? Bp[1] : 0.f;
            bv.z = (bcol + 2 < Nn) ? Bp[2] : 0.f;
            bv.w = (bcol + 3 < Nn) ? Bp[3] : 0.f;
        }
        Bs[kb][bc + 0] = bv.x;
        Bs[kb][bc + 1] = bv.y;
        Bs[kb][bc + 2] = bv.z;
        Bs[kb][bc + 3] = bv.w;

        __syncthreads();

#pragma unroll
        for (int kk = 0; kk < BK; ++kk) {
            float a[4], bb[4];
#pragma unroll
            for (int i = 0; i < 4; ++i) a[i] = As[kk][ty * 4 + i];
#pragma unroll
            for (int j = 0; j < 4; ++j) bb[j] = Bs[kk][tx * 4 + j];
#pragma unroll
            for (int i = 0; i < 4; ++i)
#pragma unroll
                for (int j = 0; j < 4; ++j)
                    acc[i][j] = fmaf(a[i], bb[j], acc[i][j]);
        }
        __syncthreads();
    }

#pragma unroll
    for (int i = 0; i < 4; ++i) {
        int row = m0 + ty * 4 + i;
#pragma unroll
        for (int j = 0; j < 4; ++j) {
            int col = n0 + tx * 4 + j;
            if (col < Nn) {
                float v = acc[i][j];
                if (EPI == 1) {
                    v += bias[col];
                    v = fmaxf(v, 0.f) + log1pf(expf(-fabsf(v)));   // stable softplus
                } else if (EPI == 2) {
                    v += add[(size_t)row * ldc + col];
                }
                C[(size_t)row * ldc + col] = v;
            }
        }
    }
}

// ---------------- Causal depthwise conv (K=4) + SiLU ----------------
__global__ void conv_silu_kernel(const float* __restrict__ xz, const float* __restrict__ cw,
                                 const float* __restrict__ cb, float* __restrict__ u) {
    int idx = blockIdx.x * blockDim.x + threadIdx.x;   // B*L*DI
    int c = idx & (DI_ - 1);
    int bl = idx >> 11;
    int l = bl & (L_ - 1);
    float4 w4 = ((const float4*)cw)[c];
    float acc = cb[c];
    const float* base = xz + (size_t)bl * (2 * DI_) + c;   // xi part of xz
    if (l >= 3) {
        acc = fmaf(base[-(size_t)3 * 2 * DI_], w4.x, acc);
        acc = fmaf(base[-(size_t)2 * 2 * DI_], w4.y, acc);
        acc = fmaf(base[-(size_t)1 * 2 * DI_], w4.z, acc);
        acc = fmaf(base[0],                    w4.w, acc);
    } else {
        if (l >= 3) acc = fmaf(*(base - 3 * 2 * DI_), w4.x, acc);
        if (l >= 2) acc = fmaf(*(base - 2 * 2 * DI_), w4.y, acc);
        if (l >= 1) acc = fmaf(*(base - 1 * 2 * DI_), w4.z, acc);
        acc = fmaf(base[0], w4.w, acc);
    }
    u[idx] = acc / (1.f + expf(-acc));   // silu
}

// ---------------- Selective scan (serial over L), fused gate ----------------
// One thread per (b,c,n). 16 threads (n) reduce via shfl. yz = (sum_n hs*C + u*D) * silu(z)
__global__ void scan_kernel(const float* __restrict__ dt, const float* __restrict__ u,
                            const float* __restrict__ proj, const float* __restrict__ xz,
                            const float* __restrict__ A_log, const float* __restrict__ D_param,
                            float* __restrict__ yz) {
    int t = threadIdx.x;          // 256 = 16 groups x 16 n
    int g = t >> 4;
    int n = t & 15;
    int bc = blockIdx.x * 16 + g;      // 0..B*DI-1
    int b = bc >> 11;                  // / DI
    int c = bc & (DI_ - 1);

    float A = -expf(A_log[c * N_ + n]);
    float Dp = D_param[c];
    float hstate = 0.f;

    const float* dt_p = dt + (size_t)b * L_ * DI_ + c;
    const float* u_p  = u  + (size_t)b * L_ * DI_ + c;
    const float* z_p  = xz + (size_t)b * L_ * (2 * DI_) + DI_ + c;
    const float* pj   = proj + (size_t)b * L_ * 96;
    float* y_p = yz + (size_t)b * L_ * DI_ + c;

    for (int l = 0; l < L_; ++l) {
        float dtv = dt_p[(size_t)l * DI_];
        float uv  = u_p[(size_t)l * DI_];
        float Bv  = pj[l * 96 + R_ + n];
        float Cv  = pj[l * 96 + R_ + N_ + n];
        float dA = expf(dtv * A);
        hstate = fmaf(dA, hstate, dtv * uv * Bv);
        float p = hstate * Cv;
        p += __shfl_xor(p, 1, 16);
        p += __shfl_xor(p, 2, 16);
        p += __shfl_xor(p, 4, 16);
        p += __shfl_xor(p, 8, 16);
        if (n == 0) {
            float zv = z_p[(size_t)l * (2 * DI_)];
            float sz = zv / (1.f + expf(-zv));
            y_p[(size_t)l * DI_] = (p + uv * Dp) * sz;
        }
    }
}

extern "C" void kernel_launch(void* const* d_in, const int* in_sizes, int n_in,
                              void* d_out, int out_size, void* d_ws, size_t ws_size,
                              hipStream_t stream) {
    const float* x       = (const float*)d_in[0];
    const float* ln_w    = (const float*)d_in[1];
    const float* ln_b    = (const float*)d_in[2];
    const float* W_in    = (const float*)d_in[3];
    const float* conv_w  = (const float*)d_in[4];
    const float* conv_b  = (const float*)d_in[5];
    const float* W_x     = (const float*)d_in[6];
    const float* W_dt    = (const float*)d_in[7];
    const float* b_dt    = (const float*)d_in[8];
    const float* A_log   = (const float*)d_in[9];
    const float* D_param = (const float*)d_in[10];
    const float* W_out   = (const float*)d_in[11];
    float* out = (float*)d_out;

    float* ws   = (float*)d_ws;
    float* h    = ws;                          // BL x D        (2M)
    float* xz   = h    + (size_t)BL_ * D_;     // BL x 2DI      (8M)
    float* u    = xz   + (size_t)BL_ * 2 * DI_;// BL x DI       (4M)
    float* proj = u    + (size_t)BL_ * DI_;    // BL x 96
    float* dt   = proj + (size_t)BL_ * 96;     // BL x DI       (4M)
    float* yz   = dt   + (size_t)BL_ * DI_;    // BL x DI       (4M)

    // 1. LayerNorm
    ln_kernel<<<BL_, 256, 0, stream>>>(x, ln_w, ln_b, h);

    // 2. xz = h @ W_in   (2048x1024 @ 1024x4096)
    gemm_kernel<0><<<dim3(2 * DI_ / 64, BL_ / 64), 256, 0, stream>>>(
        h, D_, W_in, 2 * DI_, xz, 2 * DI_, BL_, 2 * DI_, D_, nullptr, nullptr);

    // 3. u = silu(causal_conv(xi))
    conv_silu_kernel<<<(BL_ * DI_) / 256, 256, 0, stream>>>(xz, conv_w, conv_b, u);

    // 4. proj = u @ W_x   (2048x2048 @ 2048x96)
    gemm_kernel<0><<<dim3(2, BL_ / 64), 256, 0, stream>>>(
        u, DI_, W_x, 96, proj, 96, BL_, 96, DI_, nullptr, nullptr);

    // 5. dt = softplus(dt_r @ W_dt + b_dt)   (2048x64 @ 64x2048)
    gemm_kernel<1><<<dim3(DI_ / 64, BL_ / 64), 256, 0, stream>>>(
        proj, 96, W_dt, DI_, dt, DI_, BL_, DI_, R_, b_dt, nullptr);

    // 6. selective scan + gate: yz
    scan_kernel<<<(B_ * DI_) / 16, 256, 0, stream>>>(dt, u, proj, xz, A_log, D_param, yz);

    // 7. out = x + yz @ W_out   (2048x2048 @ 2048x1024)
    gemm_kernel<2><<<dim3(D_ / 64, BL_ / 64), 256, 0, stream>>>(
        yz, DI_, W_out, D_, out, D_, BL_, D_, DI_, nullptr, x);
}

// Round 2
// 819.327 us; speedup vs baseline: 1.7650x; 1.7650x over previous
//
#include <hip/hip_runtime.h>
#include <hip/hip_bf16.h>
#include <math.h>

#define B_ 2
#define L_ 1024
#define D_ 1024
#define DI_ 2048
#define K_ 4
#define N_ 16
#define R_ 64
#define BL_ (B_ * L_)
#define EPS_ 1e-5f

#define IDX(l) ((l) + ((l) >> 6))   // pad every 64 floats -> kills chunk-stride bank conflicts

// ---------------- LayerNorm: one block per row of D=1024 ----------------
__global__ void ln_kernel(const float* __restrict__ x, const float* __restrict__ w,
                          const float* __restrict__ b, float* __restrict__ h) {
    int row = blockIdx.x;              // 0..BL-1
    const float* xr = x + (size_t)row * D_;
    float4 v = ((const float4*)xr)[threadIdx.x];   // 256 threads * 4 = 1024

    __shared__ float red[4];
    // --- mean ---
    float s = v.x + v.y + v.z + v.w;
    for (int off = 1; off < 64; off <<= 1) s += __shfl_xor(s, off, 64);
    if ((threadIdx.x & 63) == 0) red[threadIdx.x >> 6] = s;
    __syncthreads();
    float mu = (red[0] + red[1] + red[2] + red[3]) * (1.0f / D_);
    __syncthreads();
    // --- var ---
    float cx = v.x - mu, cy = v.y - mu, cz = v.z - mu, cw = v.w - mu;
    float sq = cx*cx + cy*cy + cz*cz + cw*cw;
    for (int off = 1; off < 64; off <<= 1) sq += __shfl_xor(sq, off, 64);
    if ((threadIdx.x & 63) == 0) red[threadIdx.x >> 6] = sq;
    __syncthreads();
    float var = (red[0] + red[1] + red[2] + red[3]) * (1.0f / D_);
    float rstd = rsqrtf(var + EPS_);

    float4 wv = ((const float4*)w)[threadIdx.x];
    float4 bv = ((const float4*)b)[threadIdx.x];
    float4 o;
    o.x = cx * rstd * wv.x + bv.x;
    o.y = cy * rstd * wv.y + bv.y;
    o.z = cz * rstd * wv.z + bv.z;
    o.w = cw * rstd * wv.w + bv.w;
    ((float4*)(h + (size_t)row * D_))[threadIdx.x] = o;
}

// ---------------- Generic fp32 tiled GEMM: C = A(MxK) * B(KxN) ----------------
// EPI 0: none; EPI 1: softplus(acc + bias[col]); EPI 2: acc + add[row*ldc+col]
template <int EPI>
__global__ __launch_bounds__(256) void gemm_kernel(
        const float* __restrict__ A, int lda,
        const float* __restrict__ Bm, int ldb,
        float* __restrict__ C, int ldc,
        int M, int Nn, int Kk,
        const float* __restrict__ bias,
        const float* __restrict__ add) {
    const int BM = 64, BN = 64, BK = 16;
    __shared__ float As[BK][BM + 4];
    __shared__ float Bs[BK][BN];

    int tid = threadIdx.x;
    int m0 = blockIdx.y * BM;
    int n0 = blockIdx.x * BN;

    int ar = tid >> 2;           // 0..63 row within A tile
    int ak = (tid & 3) << 2;     // 0,4,8,12 k-offset
    int kb = tid >> 4;           // 0..15 k row of B tile
    int bc = (tid & 15) << 2;    // 0..60 col offset
    int ty = tid >> 4;           // 0..15
    int tx = tid & 15;           // 0..15

    float acc[4][4] = {};

    for (int k0 = 0; k0 < Kk; k0 += BK) {
        const float* Ap = A + (size_t)(m0 + ar) * lda + (k0 + ak);
        float4 av = *(const float4*)Ap;
        As[ak + 0][ar] = av.x;
        As[ak + 1][ar] = av.y;
        As[ak + 2][ar] = av.z;
        As[ak + 3][ar] = av.w;

        int bcol = n0 + bc;
        const float* Bp = Bm + (size_t)(k0 + kb) * ldb + bcol;
        float4 bv;
        if (bcol + 3 < Nn) {
            bv = *(const float4*)Bp;
        } else {
            bv.x = (bcol + 0 < Nn) ? Bp[0] : 0.f;
            bv.y = (bcol + 1 < Nn) ? Bp[1] : 0.f;
            bv.z = (bcol + 2 < Nn) ? Bp[2] : 0.f;
            bv.w = (bcol + 3 < Nn) ? Bp[3] : 0.f;
        }
        Bs[kb][bc + 0] = bv.x;
        Bs[kb][bc + 1] = bv.y;
        Bs[kb][bc + 2] = bv.z;
        Bs[kb][bc + 3] = bv.w;

        __syncthreads();

#pragma unroll
        for (int kk = 0; kk < BK; ++kk) {
            float a[4], bb[4];
#pragma unroll
            for (int i = 0; i < 4; ++i) a[i] = As[kk][ty * 4 + i];
#pragma unroll
            for (int j = 0; j < 4; ++j) bb[j] = Bs[kk][tx * 4 + j];
#pragma unroll
            for (int i = 0; i < 4; ++i)
#pragma unroll
                for (int j = 0; j < 4; ++j)
                    acc[i][j] = fmaf(a[i], bb[j], acc[i][j]);
        }
        __syncthreads();
    }

#pragma unroll
    for (int i = 0; i < 4; ++i) {
        int row = m0 + ty * 4 + i;
#pragma unroll
        for (int j = 0; j < 4; ++j) {
            int col = n0 + tx * 4 + j;
            if (col < Nn) {
                float v = acc[i][j];
                if (EPI == 1) {
                    v += bias[col];
                    v = fmaxf(v, 0.f) + log1pf(expf(-fabsf(v)));   // stable softplus
                } else if (EPI == 2) {
                    v += add[(size_t)row * ldc + col];
                }
                C[(size_t)row * ldc + col] = v;
            }
        }
    }
}

// ---------------- Causal depthwise conv (K=4) + SiLU ----------------
__global__ void conv_silu_kernel(const float* __restrict__ xz, const float* __restrict__ cw,
                                 const float* __restrict__ cb, float* __restrict__ u) {
    int idx = blockIdx.x * blockDim.x + threadIdx.x;   // B*L*DI
    int c = idx & (DI_ - 1);
    int bl = idx >> 11;
    int l = bl & (L_ - 1);
    float4 w4 = ((const float4*)cw)[c];
    float acc = cb[c];
    const float* base = xz + (size_t)bl * (2 * DI_) + c;   // xi part of xz
    if (l >= 3) {
        acc = fmaf(base[-(size_t)3 * 2 * DI_], w4.x, acc);
        acc = fmaf(base[-(size_t)2 * 2 * DI_], w4.y, acc);
        acc = fmaf(base[-(size_t)1 * 2 * DI_], w4.z, acc);
        acc = fmaf(base[0],                    w4.w, acc);
    } else {
        if (l >= 2) acc = fmaf(*(base - 2 * 2 * DI_), w4.y, acc);
        if (l >= 1) acc = fmaf(*(base - 1 * 2 * DI_), w4.z, acc);
        acc = fmaf(base[0], w4.w, acc);
    }
    u[idx] = acc / (1.f + expf(-acc));   // silu
}

// ---------------- Chunk-parallel selective scan + fused gate ----------------
// One block per (b,c): 256 threads = 16 chunks (64 l each) x 16 n.
// Phase 1: per-chunk (prod dA, local scan). Phase 2: serial combine over 16 chunks.
// Phase 3: re-walk chunk with carry-in, reduce over n, y = (h.C + u*D) * silu(z).
__global__ __launch_bounds__(256) void scan_chunked(
        const float* __restrict__ dt, const float* __restrict__ u,
        const float* __restrict__ proj, const float* __restrict__ xz,
        const float* __restrict__ A_log, const float* __restrict__ D_param,
        float* __restrict__ yz) {
    int bc = blockIdx.x;               // 0..B*DI-1
    int b = bc >> 11;
    int c = bc & (DI_ - 1);
    int t = threadIdx.x;
    int chunk = t >> 4;                // 0..15
    int n = t & 15;

    __shared__ float dt_s[L_ + 16];
    __shared__ float u_s[L_ + 16];
    __shared__ float sA[16][16];
    __shared__ float sB[16][16];

    const size_t base_blc = (size_t)b * L_ * DI_ + c;
    for (int l = t; l < L_; l += 256) {
        dt_s[IDX(l)] = dt[base_blc + (size_t)l * DI_];
        u_s[IDX(l)]  = u [base_blc + (size_t)l * DI_];
    }
    __syncthreads();

    float A = -expf(A_log[c * N_ + n]);
    int l0 = chunk * 64;
    const float* pj = proj + (size_t)b * L_ * 96;

    // Phase 1: chunk-local scan
    float a = 1.f, acc = 0.f;
#pragma unroll 8
    for (int i = 0; i < 64; ++i) {
        int l = l0 + i;
        int il = IDX(l);
        float dA = expf(dt_s[il] * A);
        float Bv = pj[l * 96 + R_ + n];
        a *= dA;
        acc = fmaf(dA, acc, dt_s[il] * u_s[il] * Bv);
    }
    sA[chunk][n] = a;
    sB[chunk][n] = acc;
    __syncthreads();

    // Phase 2: serial combine across chunks (threads 0..15, one per n)
    if (t < 16) {
        float hc = 0.f;
#pragma unroll
        for (int j = 0; j < 16; ++j) {
            float aj = sA[j][t];
            float bj = sB[j][t];
            sB[j][t] = hc;            // repurpose: carry-in for chunk j
            hc = fmaf(aj, hc, bj);
        }
    }
    __syncthreads();
    float h = sB[chunk][n];           // carry-in state

    // Phase 3: re-walk with running state; output
    float Dp = D_param[c];
    const float* z_p = xz + (size_t)b * L_ * (2 * DI_) + DI_ + c;
    float* y_p = yz + base_blc;
#pragma unroll 4
    for (int i = 0; i < 64; ++i) {
        int l = l0 + i;
        int il = IDX(l);
        float dtv = dt_s[il], uv = u_s[il];
        float dA = expf(dtv * A);
        float Bv = pj[l * 96 + R_ + n];
        float Cv = pj[l * 96 + R_ + N_ + n];
        h = fmaf(dA, h, dtv * uv * Bv);
        float p = h * Cv;
        p += __shfl_xor(p, 1, 16);
        p += __shfl_xor(p, 2, 16);
        p += __shfl_xor(p, 4, 16);
        p += __shfl_xor(p, 8, 16);
        if (n == 0) {
            float zv = z_p[(size_t)l * (2 * DI_)];
            float sz = zv / (1.f + expf(-zv));
            y_p[(size_t)l * DI_] = fmaf(uv, Dp, p) * sz;
        }
    }
}

extern "C" void kernel_launch(void* const* d_in, const int* in_sizes, int n_in,
                              void* d_out, int out_size, void* d_ws, size_t ws_size,
                              hipStream_t stream) {
    const float* x       = (const float*)d_in[0];
    const float* ln_w    = (const float*)d_in[1];
    const float* ln_b    = (const float*)d_in[2];
    const float* W_in    = (const float*)d_in[3];
    const float* conv_w  = (const float*)d_in[4];
    const float* conv_b  = (const float*)d_in[5];
    const float* W_x     = (const float*)d_in[6];
    const float* W_dt    = (const float*)d_in[7];
    const float* b_dt    = (const float*)d_in[8];
    const float* A_log   = (const float*)d_in[9];
    const float* D_param = (const float*)d_in[10];
    const float* W_out   = (const float*)d_in[11];
    float* out = (float*)d_out;

    float* ws   = (float*)d_ws;
    float* h    = ws;                          // BL x D        (2M)
    float* xz   = h    + (size_t)BL_ * D_;     // BL x 2DI      (8M)
    float* u    = xz   + (size_t)BL_ * 2 * DI_;// BL x DI       (4M)
    float* proj = u    + (size_t)BL_ * DI_;    // BL x 96
    float* dt   = proj + (size_t)BL_ * 96;     // BL x DI       (4M)
    float* yz   = dt   + (size_t)BL_ * DI_;    // BL x DI       (4M)

    // 1. LayerNorm
    ln_kernel<<<BL_, 256, 0, stream>>>(x, ln_w, ln_b, h);

    // 2. xz = h @ W_in   (2048x1024 @ 1024x4096)
    gemm_kernel<0><<<dim3(2 * DI_ / 64, BL_ / 64), 256, 0, stream>>>(
        h, D_, W_in, 2 * DI_, xz, 2 * DI_, BL_, 2 * DI_, D_, nullptr, nullptr);

    // 3. u = silu(causal_conv(xi))
    conv_silu_kernel<<<(BL_ * DI_) / 256, 256, 0, stream>>>(xz, conv_w, conv_b, u);

    // 4. proj = u @ W_x   (2048x2048 @ 2048x96)
    gemm_kernel<0><<<dim3(2, BL_ / 64), 256, 0, stream>>>(
        u, DI_, W_x, 96, proj, 96, BL_, 96, DI_, nullptr, nullptr);

    // 5. dt = softplus(dt_r @ W_dt + b_dt)   (2048x64 @ 64x2048)
    gemm_kernel<1><<<dim3(DI_ / 64, BL_ / 64), 256, 0, stream>>>(
        proj, 96, W_dt, DI_, dt, DI_, BL_, DI_, R_, b_dt, nullptr);

    // 6. chunk-parallel selective scan + gate
    scan_chunked<<<B_ * DI_, 256, 0, stream>>>(dt, u, proj, xz, A_log, D_param, yz);

    // 7. out = x + yz @ W_out   (2048x2048 @ 2048x1024)
    gemm_kernel<2><<<dim3(D_ / 64, BL_ / 64), 256, 0, stream>>>(
        yz, DI_, W_out, D_, out, D_, BL_, D_, DI_, nullptr, x);
}

// Round 3
// 429.320 us; speedup vs baseline: 3.3683x; 1.9084x over previous
//
#include <hip/hip_runtime.h>
#include <hip/hip_bf16.h>
#include <math.h>

#define B_ 2
#define L_ 1024
#define D_ 1024
#define DI_ 2048
#define K_ 4
#define N_ 16
#define R_ 64
#define BL_ (B_ * L_)
#define EPS_ 1e-5f

#define IDX(l) ((l) + ((l) >> 6))

typedef __attribute__((ext_vector_type(8))) short short8;
typedef __attribute__((ext_vector_type(4))) float f32x4;

__device__ inline unsigned short f2bf(float f) {
    unsigned u = __float_as_uint(f);
    unsigned r = (u + 0x7fffu + ((u >> 16) & 1u)) >> 16;
    return (unsigned short)r;
}
__device__ inline float bf2f(unsigned short s) {
    return __uint_as_float(((unsigned)s) << 16);
}
__device__ inline void gl_lds16(const void* g, void* l) {
    __builtin_amdgcn_global_load_lds(
        (const __attribute__((address_space(1))) void*)g,
        (__attribute__((address_space(3))) void*)l, 16, 0, 0);
}

// ---------------- LayerNorm -> bf16 output ----------------
__global__ void ln_kernel(const float* __restrict__ x, const float* __restrict__ w,
                          const float* __restrict__ b, unsigned short* __restrict__ hb) {
    int row = blockIdx.x;
    const float* xr = x + (size_t)row * D_;
    float4 v = ((const float4*)xr)[threadIdx.x];

    __shared__ float red[4];
    float s = v.x + v.y + v.z + v.w;
    for (int off = 1; off < 64; off <<= 1) s += __shfl_xor(s, off, 64);
    if ((threadIdx.x & 63) == 0) red[threadIdx.x >> 6] = s;
    __syncthreads();
    float mu = (red[0] + red[1] + red[2] + red[3]) * (1.0f / D_);
    __syncthreads();
    float cx = v.x - mu, cy = v.y - mu, cz = v.z - mu, cw = v.w - mu;
    float sq = cx*cx + cy*cy + cz*cz + cw*cw;
    for (int off = 1; off < 64; off <<= 1) sq += __shfl_xor(sq, off, 64);
    if ((threadIdx.x & 63) == 0) red[threadIdx.x >> 6] = sq;
    __syncthreads();
    float var = (red[0] + red[1] + red[2] + red[3]) * (1.0f / D_);
    float rstd = rsqrtf(var + EPS_);

    float4 wv = ((const float4*)w)[threadIdx.x];
    float4 bv = ((const float4*)b)[threadIdx.x];
    ushort4 o;
    o.x = f2bf(cx * rstd * wv.x + bv.x);
    o.y = f2bf(cy * rstd * wv.y + bv.y);
    o.z = f2bf(cz * rstd * wv.z + bv.z);
    o.w = f2bf(cw * rstd * wv.w + bv.w);
    ((ushort4*)(hb + (size_t)row * D_))[threadIdx.x] = o;
}

// ---------------- Transpose + cast: W (KxN f32) -> WT (NxK bf16) ----------------
__global__ void transpose_cast(const float* __restrict__ W, unsigned short* __restrict__ WT,
                               int K, int N) {
    __shared__ float tile[32][33];
    int k0 = blockIdx.y * 32, n0 = blockIdx.x * 32;
    int tr = threadIdx.x >> 5;   // 0..7
    int tc = threadIdx.x & 31;
#pragma unroll
    for (int i = 0; i < 4; ++i)
        tile[tr + i*8][tc] = W[(size_t)(k0 + tr + i*8) * N + n0 + tc];
    __syncthreads();
#pragma unroll
    for (int i = 0; i < 4; ++i)
        WT[(size_t)(n0 + tr + i*8) * K + k0 + tc] = f2bf(tile[tc][tr + i*8]);
}

// ---------------- MFMA bf16 GEMM: C(MxN) = A(MxK) * BT(NxK)^T ----------------
// 128 x BN tile, BK=32, 4 waves (2x2), global_load_lds staging, XOR-swizzled LDS.
// MODE 0: C = acc (plain store). MODE 1: atomicAdd(C, acc) (split-K / pre-initialized C).
template <int BN, int MODE>
__global__ __launch_bounds__(256) void mfma_gemm_bt(
        const unsigned short* __restrict__ A,  int lda,
        const unsigned short* __restrict__ BT, int ldb,
        float* __restrict__ C, int ldc, int Kchunk) {
    constexpr int NT = BN / 32;                 // 16-col tiles per wave
    __shared__ unsigned short As[128 * 32];
    __shared__ unsigned short Bs[BN * 32];

    int tid = threadIdx.x;
    int wave = tid >> 6, lane = tid & 63;
    int lane15 = lane & 15, quad = lane >> 4;
    int wr = wave >> 1, wc = wave & 1;

    int m0 = blockIdx.y * 128;
    int n0 = blockIdx.x * BN;
    int kbeg = blockIdx.z * Kchunk;
    int kend = kbeg + Kchunk;

    f32x4 acc[4][NT];
#pragma unroll
    for (int i = 0; i < 4; ++i)
#pragma unroll
        for (int j = 0; j < NT; ++j) acc[i][j] = (f32x4){0.f, 0.f, 0.f, 0.f};

    constexpr int ACALLS = 8;                   // 128 rows * 4 cells / 64 lanes
    constexpr int BCALLS = BN * 4 / 64;

    for (int k0 = kbeg; k0 < kend; k0 += 32) {
        __syncthreads();
        for (int c = wave; c < ACALLS + BCALLS; c += 4) {
            if (c < ACALLS) {
                int cell = c * 64 + lane;
                int m = cell >> 2, s = cell & 3;
                int q = s ^ (m & 3) ^ ((m >> 2) & 3);
                gl_lds16(A + (size_t)(m0 + m) * lda + k0 + q * 8, &As[c * 512]);
            } else {
                int cell = (c - ACALLS) * 64 + lane;
                int n = cell >> 2, s = cell & 3;
                int q = s ^ (n & 3) ^ ((n >> 2) & 3);
                gl_lds16(BT + (size_t)(n0 + n) * ldb + k0 + q * 8, &Bs[(c - ACALLS) * 512]);
            }
        }
        __syncthreads();

        short8 af[4], bfr[NT];
#pragma unroll
        for (int i = 0; i < 4; ++i) {
            int m = wr * 64 + i * 16 + lane15;
            int s = quad ^ (m & 3) ^ ((m >> 2) & 3);
            af[i] = *(const short8*)&As[m * 32 + s * 8];
        }
#pragma unroll
        for (int j = 0; j < NT; ++j) {
            int n = wc * (NT * 16) + j * 16 + lane15;
            int s = quad ^ (n & 3) ^ ((n >> 2) & 3);
            bfr[j] = *(const short8*)&Bs[n * 32 + s * 8];
        }
#pragma unroll
        for (int i = 0; i < 4; ++i)
#pragma unroll
            for (int j = 0; j < NT; ++j)
                acc[i][j] = __builtin_amdgcn_mfma_f32_16x16x32_bf16(af[i], bfr[j], acc[i][j], 0, 0, 0);
    }

#pragma unroll
    for (int i = 0; i < 4; ++i) {
        int row = m0 + wr * 64 + i * 16 + quad * 4;
#pragma unroll
        for (int j = 0; j < NT; ++j) {
            int col = n0 + wc * (NT * 16) + j * 16 + lane15;
#pragma unroll
            for (int r = 0; r < 4; ++r) {
                float v = acc[i][j][r];
                size_t off = (size_t)(row + r) * ldc + col;
                if (MODE == 0) C[off] = v;
                else atomicAdd(&C[off], v);
            }
        }
    }
}

// ---------------- fp32 tiled GEMM (kept for dt: K=64) ----------------
template <int EPI>
__global__ __launch_bounds__(256) void gemm_kernel(
        const float* __restrict__ A, int lda,
        const float* __restrict__ Bm, int ldb,
        float* __restrict__ C, int ldc,
        int M, int Nn, int Kk,
        const float* __restrict__ bias) {
    const int BK = 16;
    __shared__ float As[BK][64 + 4];
    __shared__ float Bs[BK][64];

    int tid = threadIdx.x;
    int m0 = blockIdx.y * 64;
    int n0 = blockIdx.x * 64;
    int ar = tid >> 2, ak = (tid & 3) << 2;
    int kb = tid >> 4, bc = (tid & 15) << 2;
    int ty = tid >> 4, tx = tid & 15;

    float acc[4][4] = {};
    for (int k0 = 0; k0 < Kk; k0 += BK) {
        const float* Ap = A + (size_t)(m0 + ar) * lda + (k0 + ak);
        float4 av = *(const float4*)Ap;
        As[ak + 0][ar] = av.x; As[ak + 1][ar] = av.y;
        As[ak + 2][ar] = av.z; As[ak + 3][ar] = av.w;

        const float* Bp = Bm + (size_t)(k0 + kb) * ldb + n0 + bc;
        float4 bv = *(const float4*)Bp;
        Bs[kb][bc + 0] = bv.x; Bs[kb][bc + 1] = bv.y;
        Bs[kb][bc + 2] = bv.z; Bs[kb][bc + 3] = bv.w;
        __syncthreads();
#pragma unroll
        for (int kk = 0; kk < BK; ++kk) {
            float a[4], bb[4];
#pragma unroll
            for (int i = 0; i < 4; ++i) a[i] = As[kk][ty * 4 + i];
#pragma unroll
            for (int j = 0; j < 4; ++j) bb[j] = Bs[kk][tx * 4 + j];
#pragma unroll
            for (int i = 0; i < 4; ++i)
#pragma unroll
                for (int j = 0; j < 4; ++j)
                    acc[i][j] = fmaf(a[i], bb[j], acc[i][j]);
        }
        __syncthreads();
    }
#pragma unroll
    for (int i = 0; i < 4; ++i) {
        int row = m0 + ty * 4 + i;
#pragma unroll
        for (int j = 0; j < 4; ++j) {
            int col = n0 + tx * 4 + j;
            float v = acc[i][j];
            if (EPI == 1) {
                v += bias[col];
                v = fmaxf(v, 0.f) + log1pf(expf(-fabsf(v)));
            }
            C[(size_t)row * ldc + col] = v;
        }
    }
}

// ---------------- Causal depthwise conv (K=4) + SiLU -> bf16 ----------------
__global__ void conv_silu_kernel(const float* __restrict__ xz, const float* __restrict__ cw,
                                 const float* __restrict__ cb, unsigned short* __restrict__ ub) {
    int idx = blockIdx.x * blockDim.x + threadIdx.x;
    int c = idx & (DI_ - 1);
    int bl = idx >> 11;
    int l = bl & (L_ - 1);
    float4 w4 = ((const float4*)cw)[c];
    float acc = cb[c];
    const float* base = xz + (size_t)bl * (2 * DI_) + c;
    if (l >= 3) {
        acc = fmaf(base[-(size_t)3 * 2 * DI_], w4.x, acc);
        acc = fmaf(base[-(size_t)2 * 2 * DI_], w4.y, acc);
        acc = fmaf(base[-(size_t)1 * 2 * DI_], w4.z, acc);
        acc = fmaf(base[0],                    w4.w, acc);
    } else {
        if (l >= 2) acc = fmaf(*(base - 2 * 2 * DI_), w4.y, acc);
        if (l >= 1) acc = fmaf(*(base - 1 * 2 * DI_), w4.z, acc);
        acc = fmaf(base[0], w4.w, acc);
    }
    ub[idx] = f2bf(acc / (1.f + expf(-acc)));
}

// ---------------- Chunk-parallel selective scan + gate -> bf16 ----------------
__global__ __launch_bounds__(256) void scan_chunked(
        const float* __restrict__ dt, const unsigned short* __restrict__ ub,
        const float* __restrict__ proj, const float* __restrict__ xz,
        const float* __restrict__ A_log, const float* __restrict__ D_param,
        unsigned short* __restrict__ yzb) {
    int bc = blockIdx.x;
    int b = bc >> 11;
    int c = bc & (DI_ - 1);
    int t = threadIdx.x;
    int chunk = t >> 4;
    int n = t & 15;

    __shared__ float dt_s[L_ + 16];
    __shared__ float u_s[L_ + 16];
    __shared__ float sA[16][16];
    __shared__ float sB[16][16];

    const size_t base_blc = (size_t)b * L_ * DI_ + c;
    for (int l = t; l < L_; l += 256) {
        dt_s[IDX(l)] = dt[base_blc + (size_t)l * DI_];
        u_s[IDX(l)]  = bf2f(ub[base_blc + (size_t)l * DI_]);
    }
    __syncthreads();

    float A = -expf(A_log[c * N_ + n]);
    int l0 = chunk * 64;
    const float* pj = proj + (size_t)b * L_ * 96;

    float a = 1.f, acc = 0.f;
#pragma unroll 8
    for (int i = 0; i < 64; ++i) {
        int l = l0 + i;
        int il = IDX(l);
        float dA = expf(dt_s[il] * A);
        float Bv = pj[l * 96 + R_ + n];
        a *= dA;
        acc = fmaf(dA, acc, dt_s[il] * u_s[il] * Bv);
    }
    sA[chunk][n] = a;
    sB[chunk][n] = acc;
    __syncthreads();

    if (t < 16) {
        float hc = 0.f;
#pragma unroll
        for (int j = 0; j < 16; ++j) {
            float aj = sA[j][t];
            float bj = sB[j][t];
            sB[j][t] = hc;
            hc = fmaf(aj, hc, bj);
        }
    }
    __syncthreads();
    float h = sB[chunk][n];

    float Dp = D_param[c];
    const float* z_p = xz + (size_t)b * L_ * (2 * DI_) + DI_ + c;
#pragma unroll 4
    for (int i = 0; i < 64; ++i) {
        int l = l0 + i;
        int il = IDX(l);
        float dtv = dt_s[il], uv = u_s[il];
        float dA = expf(dtv * A);
        float Bv = pj[l * 96 + R_ + n];
        float Cv = pj[l * 96 + R_ + N_ + n];
        h = fmaf(dA, h, dtv * uv * Bv);
        float p = h * Cv;
        p += __shfl_xor(p, 1, 16);
        p += __shfl_xor(p, 2, 16);
        p += __shfl_xor(p, 4, 16);
        p += __shfl_xor(p, 8, 16);
        if (n == 0) {
            float zv = z_p[(size_t)l * (2 * DI_)];
            float sz = zv / (1.f + expf(-zv));
            yzb[base_blc + (size_t)l * DI_] = f2bf(fmaf(uv, Dp, p) * sz);
        }
    }
}

extern "C" void kernel_launch(void* const* d_in, const int* in_sizes, int n_in,
                              void* d_out, int out_size, void* d_ws, size_t ws_size,
                              hipStream_t stream) {
    const float* x       = (const float*)d_in[0];
    const float* ln_w    = (const float*)d_in[1];
    const float* ln_b    = (const float*)d_in[2];
    const float* W_in    = (const float*)d_in[3];
    const float* conv_w  = (const float*)d_in[4];
    const float* conv_b  = (const float*)d_in[5];
    const float* W_x     = (const float*)d_in[6];
    const float* W_dt    = (const float*)d_in[7];
    const float* b_dt    = (const float*)d_in[8];
    const float* A_log   = (const float*)d_in[9];
    const float* D_param = (const float*)d_in[10];
    const float* W_out   = (const float*)d_in[11];
    float* out = (float*)d_out;

    // workspace carve-up (bytes)
    uint8_t* p = (uint8_t*)d_ws;
    unsigned short* hb    = (unsigned short*)p;  p += (size_t)BL_ * D_ * 2;          // 4 MB
    unsigned short* WinT  = (unsigned short*)p;  p += (size_t)4096 * 1024 * 2;       // 8 MB
    float*          xz    = (float*)p;           p += (size_t)BL_ * 2 * DI_ * 4;     // 32 MB
    unsigned short* ub    = (unsigned short*)p;  p += (size_t)BL_ * DI_ * 2;         // 8 MB
    unsigned short* WxT   = (unsigned short*)p;  p += (size_t)96 * DI_ * 2;          // 0.375 MB
    float*          proj  = (float*)p;           p += (size_t)BL_ * 96 * 4;          // 0.75 MB
    float*          dt    = (float*)p;           p += (size_t)BL_ * DI_ * 4;         // 16 MB
    unsigned short* yzb   = (unsigned short*)p;  p += (size_t)BL_ * DI_ * 2;         // 8 MB
    unsigned short* WoutT = (unsigned short*)p;  p += (size_t)1024 * DI_ * 2;        // 4 MB

    // init: proj accumulators to 0; out to x (residual base for atomic GEMM7)
    hipMemsetAsync(proj, 0, (size_t)BL_ * 96 * 4, stream);
    hipMemcpyAsync(out, x, (size_t)BL_ * D_ * 4, hipMemcpyDeviceToDevice, stream);

    // weight transpose-casts (cheap: ~28 MB total)
    transpose_cast<<<dim3(4096 / 32, 1024 / 32), 256, 0, stream>>>(W_in, WinT, 1024, 4096);
    transpose_cast<<<dim3(96 / 32, DI_ / 32), 256, 0, stream>>>(W_x, WxT, DI_, 96);
    transpose_cast<<<dim3(1024 / 32, DI_ / 32), 256, 0, stream>>>(W_out, WoutT, DI_, 1024);

    // 1. LayerNorm -> bf16
    ln_kernel<<<BL_, 256, 0, stream>>>(x, ln_w, ln_b, hb);

    // 2. xz = h @ W_in  (MFMA bf16, 2048x4096x1024, 512 blocks)
    mfma_gemm_bt<128, 0><<<dim3(4096 / 128, BL_ / 128, 1), 256, 0, stream>>>(
        hb, 1024, WinT, 1024, xz, 4096, 1024);

    // 3. u = silu(conv(xi)) -> bf16
    conv_silu_kernel<<<(BL_ * DI_) / 256, 256, 0, stream>>>(xz, conv_w, conv_b, ub);

    // 4. proj += u @ W_x  (MFMA bf16, N=96, split-K=16 atomic, 256 blocks)
    mfma_gemm_bt<96, 1><<<dim3(1, BL_ / 128, 16), 256, 0, stream>>>(
        ub, DI_, WxT, DI_, proj, 96, 128);

    // 5. dt = softplus(proj[:, :64] @ W_dt + b_dt)  (fp32, K=64)
    gemm_kernel<1><<<dim3(DI_ / 64, BL_ / 64), 256, 0, stream>>>(
        proj, 96, W_dt, DI_, dt, DI_, BL_, DI_, R_, b_dt);

    // 6. chunk-parallel scan + gate -> bf16
    scan_chunked<<<B_ * DI_, 256, 0, stream>>>(dt, ub, proj, xz, A_log, D_param, yzb);

    // 7. out += yz @ W_out  (MFMA bf16, split-K=4 atomic onto residual, 512 blocks)
    mfma_gemm_bt<128, 1><<<dim3(1024 / 128, BL_ / 128, 4), 256, 0, stream>>>(
        yzb, DI_, WoutT, DI_, out, 1024, 512);
}

// Round 4
// 337.331 us; speedup vs baseline: 4.2868x; 1.2727x over previous
//
#include <hip/hip_runtime.h>
#include <hip/hip_bf16.h>
#include <math.h>

#define B_ 2
#define L_ 1024
#define D_ 1024
#define DI_ 2048
#define K_ 4
#define N_ 16
#define R_ 64
#define BL_ (B_ * L_)
#define EPS_ 1e-5f

#define IDX(l) ((l) + ((l) >> 6))

typedef __attribute__((ext_vector_type(8))) short short8;
typedef __attribute__((ext_vector_type(4))) float f32x4;

__device__ inline unsigned short f2bf(float f) {
    unsigned u = __float_as_uint(f);
    unsigned r = (u + 0x7fffu + ((u >> 16) & 1u)) >> 16;
    return (unsigned short)r;
}
__device__ inline float bf2f(unsigned short s) {
    return __uint_as_float(((unsigned)s) << 16);
}
__device__ inline float fast_silu(float z) {
    return z * __builtin_amdgcn_rcpf(1.f + __expf(-z));
}
__device__ inline void gl_lds16(const void* g, void* l) {
    __builtin_amdgcn_global_load_lds(
        (const __attribute__((address_space(1))) void*)g,
        (__attribute__((address_space(3))) void*)l, 16, 0, 0);
}

// ---------------- LayerNorm -> bf16 output ----------------
__global__ void ln_kernel(const float* __restrict__ x, const float* __restrict__ w,
                          const float* __restrict__ b, unsigned short* __restrict__ hb) {
    int row = blockIdx.x;
    const float* xr = x + (size_t)row * D_;
    float4 v = ((const float4*)xr)[threadIdx.x];

    __shared__ float red[4];
    float s = v.x + v.y + v.z + v.w;
    for (int off = 1; off < 64; off <<= 1) s += __shfl_xor(s, off, 64);
    if ((threadIdx.x & 63) == 0) red[threadIdx.x >> 6] = s;
    __syncthreads();
    float mu = (red[0] + red[1] + red[2] + red[3]) * (1.0f / D_);
    __syncthreads();
    float cx = v.x - mu, cy = v.y - mu, cz = v.z - mu, cw = v.w - mu;
    float sq = cx*cx + cy*cy + cz*cz + cw*cw;
    for (int off = 1; off < 64; off <<= 1) sq += __shfl_xor(sq, off, 64);
    if ((threadIdx.x & 63) == 0) red[threadIdx.x >> 6] = sq;
    __syncthreads();
    float var = (red[0] + red[1] + red[2] + red[3]) * (1.0f / D_);
    float rstd = rsqrtf(var + EPS_);

    float4 wv = ((const float4*)w)[threadIdx.x];
    float4 bv = ((const float4*)b)[threadIdx.x];
    ushort4 o;
    o.x = f2bf(cx * rstd * wv.x + bv.x);
    o.y = f2bf(cy * rstd * wv.y + bv.y);
    o.z = f2bf(cz * rstd * wv.z + bv.z);
    o.w = f2bf(cw * rstd * wv.w + bv.w);
    ((ushort4*)(hb + (size_t)row * D_))[threadIdx.x] = o;
}

// ---------------- Transpose + cast: W (KxN f32) -> WT (NxK bf16) ----------------
__global__ void transpose_cast(const float* __restrict__ W, unsigned short* __restrict__ WT,
                               int K, int N) {
    __shared__ float tile[32][33];
    int k0 = blockIdx.y * 32, n0 = blockIdx.x * 32;
    int tr = threadIdx.x >> 5;
    int tc = threadIdx.x & 31;
#pragma unroll
    for (int i = 0; i < 4; ++i)
        tile[tr + i*8][tc] = W[(size_t)(k0 + tr + i*8) * N + n0 + tc];
    __syncthreads();
#pragma unroll
    for (int i = 0; i < 4; ++i)
        WT[(size_t)(n0 + tr + i*8) * K + k0 + tc] = f2bf(tile[tc][tr + i*8]);
}

// ---------------- MFMA bf16 GEMM: C(MxN) = A(MxK) * BT(NxK)^T ----------------
template <int BN, int MODE>
__global__ __launch_bounds__(256) void mfma_gemm_bt(
        const unsigned short* __restrict__ A,  int lda,
        const unsigned short* __restrict__ BT, int ldb,
        float* __restrict__ C, int ldc, int Kchunk) {
    constexpr int NT = BN / 32;
    __shared__ unsigned short As[128 * 32];
    __shared__ unsigned short Bs[BN * 32];

    int tid = threadIdx.x;
    int wave = tid >> 6, lane = tid & 63;
    int lane15 = lane & 15, quad = lane >> 4;
    int wr = wave >> 1, wc = wave & 1;

    int m0 = blockIdx.y * 128;
    int n0 = blockIdx.x * BN;
    int kbeg = blockIdx.z * Kchunk;
    int kend = kbeg + Kchunk;

    f32x4 acc[4][NT];
#pragma unroll
    for (int i = 0; i < 4; ++i)
#pragma unroll
        for (int j = 0; j < NT; ++j) acc[i][j] = (f32x4){0.f, 0.f, 0.f, 0.f};

    constexpr int ACALLS = 8;
    constexpr int BCALLS = BN * 4 / 64;

    for (int k0 = kbeg; k0 < kend; k0 += 32) {
        __syncthreads();
        for (int c = wave; c < ACALLS + BCALLS; c += 4) {
            if (c < ACALLS) {
                int cell = c * 64 + lane;
                int m = cell >> 2, s = cell & 3;
                int q = s ^ (m & 3) ^ ((m >> 2) & 3);
                gl_lds16(A + (size_t)(m0 + m) * lda + k0 + q * 8, &As[c * 512]);
            } else {
                int cell = (c - ACALLS) * 64 + lane;
                int n = cell >> 2, s = cell & 3;
                int q = s ^ (n & 3) ^ ((n >> 2) & 3);
                gl_lds16(BT + (size_t)(n0 + n) * ldb + k0 + q * 8, &Bs[(c - ACALLS) * 512]);
            }
        }
        __syncthreads();

        short8 af[4], bfr[NT];
#pragma unroll
        for (int i = 0; i < 4; ++i) {
            int m = wr * 64 + i * 16 + lane15;
            int s = quad ^ (m & 3) ^ ((m >> 2) & 3);
            af[i] = *(const short8*)&As[m * 32 + s * 8];
        }
#pragma unroll
        for (int j = 0; j < NT; ++j) {
            int n = wc * (NT * 16) + j * 16 + lane15;
            int s = quad ^ (n & 3) ^ ((n >> 2) & 3);
            bfr[j] = *(const short8*)&Bs[n * 32 + s * 8];
        }
#pragma unroll
        for (int i = 0; i < 4; ++i)
#pragma unroll
            for (int j = 0; j < NT; ++j)
                acc[i][j] = __builtin_amdgcn_mfma_f32_16x16x32_bf16(af[i], bfr[j], acc[i][j], 0, 0, 0);
    }

#pragma unroll
    for (int i = 0; i < 4; ++i) {
        int row = m0 + wr * 64 + i * 16 + quad * 4;
#pragma unroll
        for (int j = 0; j < NT; ++j) {
            int col = n0 + wc * (NT * 16) + j * 16 + lane15;
#pragma unroll
            for (int r = 0; r < 4; ++r) {
                float v = acc[i][j][r];
                size_t off = (size_t)(row + r) * ldc + col;
                if (MODE == 0) C[off] = v;
                else atomicAdd(&C[off], v);
            }
        }
    }
}

// ---------------- fp32 tiled GEMM (dt: K=64) ----------------
template <int EPI>
__global__ __launch_bounds__(256) void gemm_kernel(
        const float* __restrict__ A, int lda,
        const float* __restrict__ Bm, int ldb,
        float* __restrict__ C, int ldc,
        int M, int Nn, int Kk,
        const float* __restrict__ bias) {
    const int BK = 16;
    __shared__ float As[BK][64 + 4];
    __shared__ float Bs[BK][64];

    int tid = threadIdx.x;
    int m0 = blockIdx.y * 64;
    int n0 = blockIdx.x * 64;
    int ar = tid >> 2, ak = (tid & 3) << 2;
    int kb = tid >> 4, bc = (tid & 15) << 2;
    int ty = tid >> 4, tx = tid & 15;

    float acc[4][4] = {};
    for (int k0 = 0; k0 < Kk; k0 += BK) {
        const float* Ap = A + (size_t)(m0 + ar) * lda + (k0 + ak);
        float4 av = *(const float4*)Ap;
        As[ak + 0][ar] = av.x; As[ak + 1][ar] = av.y;
        As[ak + 2][ar] = av.z; As[ak + 3][ar] = av.w;

        const float* Bp = Bm + (size_t)(k0 + kb) * ldb + n0 + bc;
        float4 bv = *(const float4*)Bp;
        Bs[kb][bc + 0] = bv.x; Bs[kb][bc + 1] = bv.y;
        Bs[kb][bc + 2] = bv.z; Bs[kb][bc + 3] = bv.w;
        __syncthreads();
#pragma unroll
        for (int kk = 0; kk < BK; ++kk) {
            float a[4], bb[4];
#pragma unroll
            for (int i = 0; i < 4; ++i) a[i] = As[kk][ty * 4 + i];
#pragma unroll
            for (int j = 0; j < 4; ++j) bb[j] = Bs[kk][tx * 4 + j];
#pragma unroll
            for (int i = 0; i < 4; ++i)
#pragma unroll
                for (int j = 0; j < 4; ++j)
                    acc[i][j] = fmaf(a[i], bb[j], acc[i][j]);
        }
        __syncthreads();
    }
#pragma unroll
    for (int i = 0; i < 4; ++i) {
        int row = m0 + ty * 4 + i;
#pragma unroll
        for (int j = 0; j < 4; ++j) {
            int col = n0 + tx * 4 + j;
            float v = acc[i][j];
            if (EPI == 1) {
                v += bias[col];
                v = fmaxf(v, 0.f) + __logf(1.f + __expf(-fabsf(v)));
            }
            C[(size_t)row * ldc + col] = v;
        }
    }
}

// ---------------- Causal depthwise conv (K=4) + SiLU -> bf16 ----------------
__global__ void conv_silu_kernel(const float* __restrict__ xz, const float* __restrict__ cw,
                                 const float* __restrict__ cb, unsigned short* __restrict__ ub) {
    int idx = blockIdx.x * blockDim.x + threadIdx.x;
    int c = idx & (DI_ - 1);
    int bl = idx >> 11;
    int l = bl & (L_ - 1);
    float4 w4 = ((const float4*)cw)[c];
    float acc = cb[c];
    const float* base = xz + (size_t)bl * (2 * DI_) + c;
    if (l >= 3) {
        acc = fmaf(base[-(size_t)3 * 2 * DI_], w4.x, acc);
        acc = fmaf(base[-(size_t)2 * 2 * DI_], w4.y, acc);
        acc = fmaf(base[-(size_t)1 * 2 * DI_], w4.z, acc);
        acc = fmaf(base[0],                    w4.w, acc);
    } else {
        if (l >= 2) acc = fmaf(*(base - 2 * 2 * DI_), w4.y, acc);
        if (l >= 1) acc = fmaf(*(base - 1 * 2 * DI_), w4.z, acc);
        acc = fmaf(base[0], w4.w, acc);
    }
    ub[idx] = f2bf(fast_silu(acc));
}

// ---------------- Prep: transpose dt/u and pre-gated silu(z) into (c, bl) ----------------
__global__ void prep_transpose(const float* __restrict__ dt, const unsigned short* __restrict__ u,
                               const float* __restrict__ xz,
                               float* __restrict__ dtT, unsigned short* __restrict__ uT,
                               unsigned short* __restrict__ szT) {
    __shared__ float t_dt[32][33];
    __shared__ unsigned short t_u[32][33];
    __shared__ unsigned short t_sz[32][33];
    int bl0 = blockIdx.y * 32, c0 = blockIdx.x * 32;
    int r = threadIdx.x >> 5;   // 0..7
    int col = threadIdx.x & 31;
#pragma unroll
    for (int i = 0; i < 4; ++i) {
        int bl = bl0 + r + i*8;
        t_dt[r + i*8][col] = dt[(size_t)bl * DI_ + c0 + col];
        t_u [r + i*8][col] = u [(size_t)bl * DI_ + c0 + col];
        float z = xz[(size_t)bl * (2 * DI_) + DI_ + c0 + col];
        t_sz[r + i*8][col] = f2bf(fast_silu(z));
    }
    __syncthreads();
#pragma unroll
    for (int i = 0; i < 4; ++i) {
        int c = c0 + r + i*8;
        dtT[(size_t)c * BL_ + bl0 + col] = t_dt[col][r + i*8];
        uT [(size_t)c * BL_ + bl0 + col] = t_u [col][r + i*8];
        szT[(size_t)c * BL_ + bl0 + col] = t_sz[col][r + i*8];
    }
}

// ---------------- Transpose back: yzT (DI x BL bf16) -> yz (BL x DI bf16) ----------------
__global__ void transpose_y(const unsigned short* __restrict__ yzT, unsigned short* __restrict__ yz) {
    __shared__ unsigned short t[32][33];
    int c0 = blockIdx.y * 32, bl0 = blockIdx.x * 32;
    int r = threadIdx.x >> 5;
    int col = threadIdx.x & 31;
#pragma unroll
    for (int i = 0; i < 4; ++i)
        t[r + i*8][col] = yzT[(size_t)(c0 + r + i*8) * BL_ + bl0 + col];
    __syncthreads();
#pragma unroll
    for (int i = 0; i < 4; ++i)
        yz[(size_t)(bl0 + r + i*8) * DI_ + c0 + col] = t[col][r + i*8];
}

// ---------------- Chunk-parallel selective scan (transposed I/O, fast exp) ----------------
__global__ __launch_bounds__(256) void scan_chunked(
        const float* __restrict__ dtT, const unsigned short* __restrict__ uT,
        const unsigned short* __restrict__ szT, const float* __restrict__ proj,
        const float* __restrict__ A_log, const float* __restrict__ D_param,
        unsigned short* __restrict__ yzT) {
    int bc = blockIdx.x;
    int b = bc >> 11;
    int c = bc & (DI_ - 1);
    int t = threadIdx.x;

    __shared__ float dt_s[L_ + 16];
    __shared__ float u_s[L_ + 16];
    __shared__ float sz_s[L_ + 16];
    __shared__ float sA[16][16];
    __shared__ float sB[16][16];
    __shared__ unsigned short ys[L_ + 16];

    const size_t tb = (size_t)c * BL_ + (size_t)b * L_;
    {   // coalesced vectorized staging: 256 threads x 4 elements
        int l = t * 4;
        int il = IDX(l);           // 4-aligned within a 64-block -> contiguous
        float4 d4 = *(const float4*)(dtT + tb + l);
        ushort4 u4 = *(const ushort4*)(uT + tb + l);
        ushort4 s4 = *(const ushort4*)(szT + tb + l);
        *(float4*)&dt_s[il] = d4;
        u_s[il + 0] = bf2f(u4.x); u_s[il + 1] = bf2f(u4.y);
        u_s[il + 2] = bf2f(u4.z); u_s[il + 3] = bf2f(u4.w);
        sz_s[il + 0] = bf2f(s4.x); sz_s[il + 1] = bf2f(s4.y);
        sz_s[il + 2] = bf2f(s4.z); sz_s[il + 3] = bf2f(s4.w);
    }
    __syncthreads();

    int chunk = t >> 4;
    int n = t & 15;
    float A = -__expf(A_log[c * N_ + n]);
    int l0 = chunk * 64;
    const float* pj = proj + (size_t)b * L_ * 96;

    // Phase 1: chunk-local scan
    float a = 1.f, acc = 0.f;
#pragma unroll 8
    for (int i = 0; i < 64; ++i) {
        int l = l0 + i;
        int il = IDX(l);
        float dtv = dt_s[il];
        float dA = __expf(dtv * A);
        float Bv = pj[l * 96 + R_ + n];
        a *= dA;
        acc = fmaf(dA, acc, dtv * u_s[il] * Bv);
    }
    sA[chunk][n] = a;
    sB[chunk][n] = acc;
    __syncthreads();

    // Phase 2: serial combine across 16 chunks
    if (t < 16) {
        float hc = 0.f;
#pragma unroll
        for (int j = 0; j < 16; ++j) {
            float aj = sA[j][t];
            float bj = sB[j][t];
            sB[j][t] = hc;
            hc = fmaf(aj, hc, bj);
        }
    }
    __syncthreads();
    float h = sB[chunk][n];

    // Phase 3: re-walk with carry-in; gate pre-computed
    float Dp = D_param[c];
#pragma unroll 4
    for (int i = 0; i < 64; ++i) {
        int l = l0 + i;
        int il = IDX(l);
        float dtv = dt_s[il], uv = u_s[il];
        float dA = __expf(dtv * A);
        float Bv = pj[l * 96 + R_ + n];
        float Cv = pj[l * 96 + R_ + N_ + n];
        h = fmaf(dA, h, dtv * uv * Bv);
        float p = h * Cv;
        p += __shfl_xor(p, 1, 16);
        p += __shfl_xor(p, 2, 16);
        p += __shfl_xor(p, 4, 16);
        p += __shfl_xor(p, 8, 16);
        if (n == 0) ys[il] = f2bf(fmaf(uv, Dp, p) * sz_s[il]);
    }
    __syncthreads();

    {   // coalesced bf16 output burst
        int l = t * 4;
        int il = IDX(l);
        *(ushort4*)(yzT + tb + l) = *(const ushort4*)&ys[il];
    }
}

extern "C" void kernel_launch(void* const* d_in, const int* in_sizes, int n_in,
                              void* d_out, int out_size, void* d_ws, size_t ws_size,
                              hipStream_t stream) {
    const float* x       = (const float*)d_in[0];
    const float* ln_w    = (const float*)d_in[1];
    const float* ln_b    = (const float*)d_in[2];
    const float* W_in    = (const float*)d_in[3];
    const float* conv_w  = (const float*)d_in[4];
    const float* conv_b  = (const float*)d_in[5];
    const float* W_x     = (const float*)d_in[6];
    const float* W_dt    = (const float*)d_in[7];
    const float* b_dt    = (const float*)d_in[8];
    const float* A_log   = (const float*)d_in[9];
    const float* D_param = (const float*)d_in[10];
    const float* W_out   = (const float*)d_in[11];
    float* out = (float*)d_out;

    uint8_t* p = (uint8_t*)d_ws;
    unsigned short* hb    = (unsigned short*)p;  p += (size_t)BL_ * D_ * 2;          // 4 MB
    unsigned short* WinT  = (unsigned short*)p;  p += (size_t)4096 * 1024 * 2;       // 8 MB
    float*          xz    = (float*)p;           p += (size_t)BL_ * 2 * DI_ * 4;     // 32 MB
    unsigned short* ub    = (unsigned short*)p;  p += (size_t)BL_ * DI_ * 2;         // 8 MB
    unsigned short* WxT   = (unsigned short*)p;  p += (size_t)96 * DI_ * 2;          // 0.375 MB
    float*          proj  = (float*)p;           p += (size_t)BL_ * 96 * 4;          // 0.75 MB
    float*          dt    = (float*)p;           p += (size_t)BL_ * DI_ * 4;         // 16 MB
    unsigned short* yzb   = (unsigned short*)p;  p += (size_t)BL_ * DI_ * 2;         // 8 MB
    unsigned short* WoutT = (unsigned short*)p;  p += (size_t)1024 * DI_ * 2;        // 4 MB
    float*          dtT   = (float*)p;           p += (size_t)BL_ * DI_ * 4;         // 16 MB
    unsigned short* uT    = (unsigned short*)p;  p += (size_t)BL_ * DI_ * 2;         // 8 MB
    unsigned short* szT   = (unsigned short*)p;  p += (size_t)BL_ * DI_ * 2;         // 8 MB
    unsigned short* yzT   = (unsigned short*)p;  p += (size_t)BL_ * DI_ * 2;         // 8 MB

    hipMemsetAsync(proj, 0, (size_t)BL_ * 96 * 4, stream);
    hipMemcpyAsync(out, x, (size_t)BL_ * D_ * 4, hipMemcpyDeviceToDevice, stream);

    transpose_cast<<<dim3(4096 / 32, 1024 / 32), 256, 0, stream>>>(W_in, WinT, 1024, 4096);
    transpose_cast<<<dim3(96 / 32, DI_ / 32), 256, 0, stream>>>(W_x, WxT, DI_, 96);
    transpose_cast<<<dim3(1024 / 32, DI_ / 32), 256, 0, stream>>>(W_out, WoutT, DI_, 1024);

    // 1. LayerNorm -> bf16
    ln_kernel<<<BL_, 256, 0, stream>>>(x, ln_w, ln_b, hb);

    // 2. xz = h @ W_in  (MFMA bf16)
    mfma_gemm_bt<128, 0><<<dim3(4096 / 128, BL_ / 128, 1), 256, 0, stream>>>(
        hb, 1024, WinT, 1024, xz, 4096, 1024);

    // 3. u = silu(conv(xi)) -> bf16
    conv_silu_kernel<<<(BL_ * DI_) / 256, 256, 0, stream>>>(xz, conv_w, conv_b, ub);

    // 4. proj += u @ W_x  (MFMA bf16, split-K=16 atomic)
    mfma_gemm_bt<96, 1><<<dim3(1, BL_ / 128, 16), 256, 0, stream>>>(
        ub, DI_, WxT, DI_, proj, 96, 128);

    // 5. dt = softplus(proj[:, :64] @ W_dt + b_dt)  (fp32, K=64)
    gemm_kernel<1><<<dim3(DI_ / 64, BL_ / 64), 256, 0, stream>>>(
        proj, 96, W_dt, DI_, dt, DI_, BL_, DI_, R_, b_dt);

    // 5b. transpose dt/u + pre-gate silu(z) into (c, bl)
    prep_transpose<<<dim3(DI_ / 32, BL_ / 32), 256, 0, stream>>>(dt, ub, xz, dtT, uT, szT);

    // 6. chunk-parallel scan + gate -> yzT (coalesced)
    scan_chunked<<<B_ * DI_, 256, 0, stream>>>(dtT, uT, szT, proj, A_log, D_param, yzT);

    // 6b. yzT -> row-major yzb for GEMM7
    transpose_y<<<dim3(BL_ / 32, DI_ / 32), 256, 0, stream>>>(yzT, yzb);

    // 7. out += yz @ W_out  (MFMA bf16, split-K=4 atomic onto residual)
    mfma_gemm_bt<128, 1><<<dim3(1024 / 128, BL_ / 128, 4), 256, 0, stream>>>(
        yzb, DI_, WoutT, DI_, out, 1024, 512);
}